// Round 2
// baseline (347.017 us; speedup 1.0000x reference)
//
#include <hip/hip_runtime.h>
#include <math.h>

#define HW (512 * 512)
#define NB 16
#define NTHR 256
#define GXS 64          // blocks per batch: 64 blocks * 256 thr * 16 px = HW
#define CH2 8           // 8 chunks of 2 px per thread = 16 px/thread
#define NSEG 256        // waves per batch = segments
#define SEGSZ 1024      // max keys per segment (16 px * 64 lanes)
#define PREP 4          // replicas for k_pix accumulator atomics

// ---- workspace layout (4-byte words). NOTHING needs pre-zeroing in the
// compaction path: k_stats writes per-block partial slots (plain stores),
// k_sel zeroes PACC+ticket for k_pix. ----
#define OFF_ACC    0                           // f [NB][GXS][52] per-block partials
#define OFF_NEGMX  (OFF_ACC + NB * GXS * 52)   // u [NB][GXS] per-block max(~negkey)
#define OFF_PACC   (OFF_NEGMX + NB * GXS)      // f [PREP][NB][4] (zeroed by k_sel)
#define OFF_TICK   (OFF_PACC + PREP * NB * 4)  // u ticket (zeroed by k_sel)
#define OFF_KDICE  (OFF_TICK + 16)             // f [NB][3] ak,bk,ck
#define OFF_TBL    (OFF_KDICE + NB * 3)        // f [NB][9][5] rows0..8={a0..a3,w}
#define OFF_THR    (OFF_TBL + NB * 45)         // f [NB]
#define OFF_FB     (OFF_THR + NB)              // u [NB]
#define OFF_NVAL   (OFF_FB + NB)               // u [NB]
#define OFF_DISCR  (OFF_NVAL + NB)             // f [NB]
#define OFF_PREFIX (OFF_DISCR + NB)            // u [NB] fallback select state
#define OFF_KKC    (OFF_PREFIX + NB)           // u [NB]
#define OFF_NEGC   (OFF_KKC + NB)              // u [NB]
#define OFF_HISTFB (OFF_NEGC + NB)             // u [4][16][256] fallback hists
#define OFF_CNTS   (OFF_HISTFB + 4 * 16 * 256) // u [NB][NSEG] per-wave seg counts
#define OFF_KEYS   (OFF_CNTS + NB * NSEG)      // u [NB][NSEG][SEGSZ] compacted keys
#define WS_FULL_BYTES ((size_t)(OFF_KEYS + NB * HW) * 4)

// acc value indices: 0-7 kcnt, 8-15 tcnt, 16-47 ksum, 48 pos, 49 ak, 50 bk, 51 ck

__device__ __forceinline__ unsigned fmap(float f) {
    unsigned u = __float_as_uint(f);
    return (u & 0x80000000u) ? ~u : (u | 0x80000000u);
}
__device__ __forceinline__ float funmap(unsigned u) {
    return (u & 0x80000000u) ? __uint_as_float(u & 0x7FFFFFFFu)
                             : __uint_as_float(~u);
}
__device__ __forceinline__ float wred(float x) {
#pragma unroll
    for (int o = 32; o; o >>= 1) x += __shfl_xor(x, o);
    return x;
}
__device__ __forceinline__ unsigned wredu(unsigned x) {
#pragma unroll
    for (int o = 32; o; o >>= 1) x += __shfl_xor(x, o);
    return x;
}
__device__ __forceinline__ unsigned wredumax(unsigned x) {
#pragma unroll
    for (int o = 32; o; o >>= 1) x = max(x, (unsigned)__shfl_xor((int)x, o));
    return x;
}
__device__ __forceinline__ unsigned long long wredull(unsigned long long x) {
#pragma unroll
    for (int o = 32; o; o >>= 1)
        x += (unsigned long long)__shfl_xor((unsigned long long)x, o);
    return x;
}

// ---------------- K1: stats + kernel-dice + segment compaction ----------------
// Latency-bound before (VALUBusy 22%, HBM 14%): 2-px chunks with A/B register
// double-buffering so the next chunk's 9 loads are in flight while the current
// chunk computes (compute/chunk ~1.2k cyc > load latency ~600 cyc).
// Pixel order per thread is identical to the old 4-px-chunk layout, so all
// float accumulation orders are preserved.
__global__ __launch_bounds__(NTHR, 4) void k_stats(const float* __restrict__ preds,
                        const int* __restrict__ text,
                        const int* __restrict__ kern,
                        const int* __restrict__ mask,
                        unsigned* __restrict__ wsu, int do_compact) {
    float* wsf = (float*)wsu;
    const int b = blockIdx.y;
    const int tid = threadIdx.x;
    const int lane = tid & 63;
    const unsigned long long lmask = (1ull << lane) - 1ull;
    __shared__ float sacc[52];
    __shared__ unsigned smx;
    if (tid < 52) sacc[tid] = 0.f;
    if (tid == 0) smx = 0u;
    __syncthreads();

    const int* tb = text + b * HW;
    const int* kb = kern + b * HW;
    const int* mb = mask + b * HW;
    const float* p0 = preds + (size_t)(b * 6 + 0) * HW;
    const float* p1 = preds + (size_t)(b * 6 + 1) * HW;
    const float* e0 = preds + (size_t)(b * 6 + 2) * HW;
    const float* e1 = e0 + HW;
    const float* e2 = e0 + 2 * HW;
    const float* e3 = e0 + 3 * HW;

    const int seg = blockIdx.x * 4 + (tid >> 6);
    unsigned* keys = wsu + OFF_KEYS + (size_t)b * HW + (size_t)seg * SEGSZ;
    unsigned segoff = 0;
    unsigned mkAll = 0u;

    float ks[32];
#pragma unroll
    for (int i = 0; i < 32; i++) ks[i] = 0.f;
    float r_ak = 0.f, r_bk = 0.f, r_ck = 0.f, r_pos = 0.f;
    unsigned kcW[8] = {0, 0, 0, 0, 0, 0, 0, 0};
    unsigned long long tpack = 0ull;  // 8x8-bit per-thread text-counts (<=16/field)

    // chunk ci (0..7): same 16 pixels per thread as the old 4-px layout, in order
#define BASE_(ci_) (blockIdx.x * (NTHR * 16) + ((ci_) >> 1) * (NTHR * 4) + ((ci_) & 1) * 2 + tid * 4)

#define LOADC(P, ci_) do {                                                   \
        const int base_ = BASE_(ci_);                                        \
        P##t = *(const int2*)(tb + base_);                                   \
        P##k = *(const int2*)(kb + base_);                                   \
        P##m = *(const int2*)(mb + base_);                                   \
        P##s = *(const float2*)(p0 + base_);                                 \
        P##q = *(const float2*)(p1 + base_);                                 \
        P##a = *(const float2*)(e0 + base_);                                 \
        P##b = *(const float2*)(e1 + base_);                                 \
        P##c = *(const float2*)(e2 + base_);                                 \
        P##d = *(const float2*)(e3 + base_);                                 \
    } while (0)

#define PIX(T, K, M, Q, A, B, C, D) do {                                     \
        bool pos_ = (T) > 0, mp_ = (M) > 0;                                  \
        float sm_ = (pos_ && mp_) ? 1.f : 0.f;                               \
        float sg_ = 1.f / (1.f + expf(-(Q)));                                \
        float ik_ = ((K) > 0) ? 1.f : 0.f;                                   \
        r_ak += sm_ * sg_ * ik_;                                             \
        r_bk += sm_ * sg_ * sg_;                                             \
        r_ck += sm_ * ik_;                                                   \
        r_pos += sm_;                                                        \
        tpack += pos_ ? (1ull << ((((unsigned)(T) - 1u) & 7u) * 8u)) : 0ull; \
        _Pragma("unroll")                                                    \
        for (int i_ = 0; i_ < 8; i_++) {                                     \
            bool hit_ = ((K) == i_ + 1);                                     \
            kcW[i_] += (unsigned)__popcll(__ballot(hit_));                   \
            float h_ = hit_ ? 1.f : 0.f;                                     \
            ks[i_ * 4 + 0] += h_ * (A);                                      \
            ks[i_ * 4 + 1] += h_ * (B);                                      \
            ks[i_ * 4 + 2] += h_ * (C);                                      \
            ks[i_ * 4 + 3] += h_ * (D);                                      \
        }                                                                    \
    } while (0)

#define PROC(P) do {                                                            \
        PIX(P##t.x, P##k.x, P##m.x, P##q.x, P##a.x, P##b.x, P##c.x, P##d.x);    \
        PIX(P##t.y, P##k.y, P##m.y, P##q.y, P##a.y, P##b.y, P##c.y, P##d.y);    \
        const unsigned long long m0_ = __ballot(P##t.x == 0);                   \
        const unsigned long long m1_ = __ballot(P##t.y == 0);                   \
        const unsigned c0_ = (unsigned)__popcll(m0_);                           \
        const unsigned c1_ = (unsigned)__popcll(m1_);                           \
        if (do_compact) {                                                       \
            if (P##t.x == 0)                                                    \
                keys[segoff + (unsigned)__popcll(m0_ & lmask)] = fmap(P##s.x);  \
            if (P##t.y == 0)                                                    \
                keys[segoff + c0_ + (unsigned)__popcll(m1_ & lmask)] = fmap(P##s.y); \
        }                                                                       \
        segoff += c0_ + c1_;                                                    \
        unsigned mk_ = 0u;                                                      \
        if (P##t.x == 0) mk_ = max(mk_, ~fmap(P##s.x));                         \
        if (P##t.y == 0) mk_ = max(mk_, ~fmap(P##s.y));                         \
        mkAll = max(mkAll, mk_);                                                \
    } while (0)

    int2 At, Ak, Am;  float2 As, Aq, Aa, Ab, Ac, Ad;
    int2 Bt, Bk, Bm;  float2 Bs, Bq, Ba, Bb, Bc, Bd;

    LOADC(A, 0);
#pragma unroll 1
    for (int cc = 0; cc < CH2 / 2; ++cc) {
        LOADC(B, cc * 2 + 1);            // prefetch: in flight during PROC(A)
        PROC(A);
        if (cc + 1 < CH2 / 2) LOADC(A, cc * 2 + 2);  // in flight during PROC(B)
        PROC(B);
    }
#undef PROC
#undef PIX
#undef LOADC
#undef BASE_

    if (lane == 0) wsu[OFF_CNTS + b * NSEG + seg] = segoff;
    mkAll = wredumax(mkAll);
    if (lane == 0) atomicMax(&smx, mkAll);

    // ---- epilogue: wave butterfly -> LDS -> one plain per-block store ----
#pragma unroll
    for (int i = 0; i < 32; i++) {
        float v = wred(ks[i]);
        if (lane == 0) atomicAdd(&sacc[16 + i], v);
    }
    {
        float v = wred(r_ak); if (lane == 0) atomicAdd(&sacc[49], v);
        v = wred(r_bk); if (lane == 0) atomicAdd(&sacc[50], v);
        v = wred(r_ck); if (lane == 0) atomicAdd(&sacc[51], v);
        v = wred(r_pos); if (lane == 0) atomicAdd(&sacc[48], v);
    }
    {
        // unpack 8x8-bit -> 2x(4x16-bit) so the 64-lane sum can't overflow
        unsigned long long lo = tpack & 0x00FF00FF00FF00FFull;          // inst 1,3,5,7
        unsigned long long hi = (tpack >> 8) & 0x00FF00FF00FF00FFull;   // inst 2,4,6,8
        lo = wredull(lo);
        hi = wredull(hi);
        if (lane == 0) {
            atomicAdd(&sacc[8 + 0], (float)(unsigned)( lo        & 0xFFFFull));
            atomicAdd(&sacc[8 + 2], (float)(unsigned)((lo >> 16) & 0xFFFFull));
            atomicAdd(&sacc[8 + 4], (float)(unsigned)((lo >> 32) & 0xFFFFull));
            atomicAdd(&sacc[8 + 6], (float)(unsigned)((lo >> 48) & 0xFFFFull));
            atomicAdd(&sacc[8 + 1], (float)(unsigned)( hi        & 0xFFFFull));
            atomicAdd(&sacc[8 + 3], (float)(unsigned)((hi >> 16) & 0xFFFFull));
            atomicAdd(&sacc[8 + 5], (float)(unsigned)((hi >> 32) & 0xFFFFull));
            atomicAdd(&sacc[8 + 7], (float)(unsigned)((hi >> 48) & 0xFFFFull));
        }
    }
    if (lane == 0) {
#pragma unroll
        for (int i = 0; i < 8; i++) atomicAdd(&sacc[i], (float)kcW[i]);
    }
    __syncthreads();
    if (tid < 52)
        wsf[OFF_ACC + (b * GXS + blockIdx.x) * 52 + tid] = sacc[tid];
    if (tid == 0)
        wsu[OFF_NEGMX + b * GXS + blockIdx.x] = smx;
}

// ---------------- K2: partial-sum + setup + OHEM threshold ----------------
__global__ void k_sel(unsigned* __restrict__ wsu, int do_select) {
    float* wsf = (float*)wsu;
    const int b = blockIdx.x;
    const int tid = threadIdx.x;   // 256 threads; tid == segment id
    const int lane = tid & 63;
    __shared__ float s_acc[52];
    __shared__ float s_avg[8][4];
    __shared__ int s_valid[8];
    __shared__ unsigned s_hist[256];
    __shared__ unsigned s_negtot;
    __shared__ unsigned s_negmax;
    __shared__ unsigned s_kk, s_prefix;

    if (tid < 52) {
        float v = 0.f;
        const float* p = wsf + OFF_ACC + b * GXS * 52 + tid;
#pragma unroll 8
        for (int r = 0; r < GXS; r++) v += p[r * 52];
        s_acc[tid] = v;
    }
    if (tid == 0) s_negtot = 0u;
    // zero the k_pix accumulators + completion ticket (block 0 only)
    if (b == 0) {
        if (tid < PREP * NB * 4) wsf[OFF_PACC + tid] = 0.f;
        if (tid == 0) wsu[OFF_TICK] = 0u;
    }
    __syncthreads();

    const unsigned myc = wsu[OFF_CNTS + b * NSEG + tid];
    {
        unsigned cw = wredu(myc);
        if (lane == 0) atomicAdd(&s_negtot, cw);
    }
    if (tid < 64) {
        unsigned m = wsu[OFF_NEGMX + b * GXS + tid];
        m = wredumax(m);
        if (tid == 0) s_negmax = m;
    }
    if (tid < 8) {
        float kcf = s_acc[tid];
        float tcf = s_acc[8 + tid];
        int valid = (kcf > 0.f && tcf > 0.f) ? 1 : 0;
        float inv = 1.f / fmaxf(kcf, 1.f);
        float w = valid ? 1.f / fmaxf(tcf, 1.f) : 0.f;
#pragma unroll
        for (int c = 0; c < 4; c++) {
            float a = s_acc[16 + tid * 4 + c] * inv;
            s_avg[tid][c] = a;
            wsf[OFF_TBL + b * 45 + (tid + 1) * 5 + c] = a;
        }
        s_valid[tid] = valid;
        wsf[OFF_TBL + b * 45 + (tid + 1) * 5 + 4] = w;
    }
    if (tid >= 8 && tid < 13) wsf[OFF_TBL + b * 45 + (tid - 8)] = 0.f;  // bg row
    if (tid >= 16 && tid < 19) wsf[OFF_KDICE + b * 3 + (tid - 16)] = s_acc[49 + (tid - 16)];
    __syncthreads();
    if (tid == 0) {
        int nval = 0;
        for (int i = 0; i < 8; i++) nval += s_valid[i];
        float L = 0.f;
        for (int i = 0; i < 8; i++)
            for (int j = i + 1; j < 8; j++)
                if (s_valid[i] && s_valid[j]) {
                    float sq = 0.f;
                    for (int c = 0; c < 4; c++) {
                        float d = s_avg[i][c] - s_avg[j][c];
                        sq += d * d;
                    }
                    float h = fmaxf(3.0f - sqrtf(sq), 0.f);
                    L += log1pf(h * h);
                }
        wsf[OFF_DISCR + b] = (nval > 1) ? L / fmaxf((float)(nval * (nval - 1)), 1.f) : 0.f;
        wsu[OFF_NVAL + b] = (unsigned)nval;
        unsigned pos = (unsigned)s_acc[48];
        unsigned neg = s_negtot;
        wsu[OFF_NEGC + b] = neg;
        unsigned nn = min(pos * 3u, neg);
        int fb = (pos == 0u || nn == 0u) ? 1 : 0;
        wsu[OFF_FB + b] = (unsigned)fb;
        wsu[OFF_KKC + b] = fb ? 0u : nn;   // fallback path state
        wsu[OFF_PREFIX + b] = 0u;
        wsf[OFF_THR + b] = 0.f;
        unsigned kk = fb ? 0u : nn;
        if (!fb && nn == neg) {
            // fast path: threshold = min negative score
            wsf[OFF_THR + b] = funmap(~s_negmax);
            kk = 0u;                        // skip radix
        }
        s_kk = kk;
        s_prefix = 0u;
    }
    __syncthreads();
    if (!do_select) return;
    if (s_kk == 0u) return;                 // uniform: fb or fast path
    const unsigned* keys = wsu + OFF_KEYS + (size_t)b * HW + (size_t)tid * SEGSZ;
    unsigned prefix = 0u;
    for (int pass = 0; pass < 4; pass++) {
        const int shift = 24 - 8 * pass;
        const unsigned fmask = (pass == 0) ? 0u : (0xFFFFFFFFu << (shift + 8));
        s_hist[tid] = 0u;
        __syncthreads();
        for (unsigned i = 0; i < myc; i++) {
            unsigned key = keys[i];
            if ((key & fmask) == prefix) atomicAdd(&s_hist[(key >> shift) & 255u], 1u);
        }
        __syncthreads();
        if (tid == 0) {
            unsigned k2 = s_kk;
            for (int bin = 255; bin >= 0; --bin) {
                unsigned c = s_hist[bin];
                if (k2 <= c) { s_prefix = prefix | (((unsigned)bin) << shift); s_kk = k2; break; }
                k2 -= c;
            }
        }
        __syncthreads();
        prefix = s_prefix;
    }
    if (tid == 0) wsf[OFF_THR + b] = funmap(prefix);
}

// ---------------- fallback radix select over raw data (only if ws too small) ----------------
__global__ void k_hist(const float* __restrict__ preds, const int* __restrict__ text,
                       unsigned* __restrict__ wsu, int pass) {
    const int b = blockIdx.y;
    const int tid = threadIdx.x;
    __shared__ unsigned h[256];
    h[tid] = 0u;
    __syncthreads();
    const unsigned prefix = wsu[OFF_PREFIX + b];
    const int shift = 24 - 8 * pass;
    const unsigned fmask = (pass == 0) ? 0u : (0xFFFFFFFFu << (shift + 8));
    const int* tb = text + b * HW;
    const float* pt = preds + (size_t)(b * 6) * HW;
    for (int p = blockIdx.x * NTHR + tid; p < HW; p += gridDim.x * NTHR) {
        if (tb[p] == 0) {
            unsigned key = fmap(pt[p]);
            if ((key & fmask) == prefix) atomicAdd(&h[(key >> shift) & 255u], 1u);
        }
    }
    __syncthreads();
    if (h[tid]) atomicAdd(&wsu[OFF_HISTFB + pass * 4096 + b * 256 + tid], h[tid]);
}
__global__ void k_select(unsigned* __restrict__ wsu, int pass) {
    int b = threadIdx.x;
    if (b >= NB) return;
    float* wsf = (float*)wsu;
    unsigned k = wsu[OFF_KKC + b];
    unsigned prefix = wsu[OFF_PREFIX + b];
    const int shift = 24 - 8 * pass;
    const unsigned* h = &wsu[OFF_HISTFB + pass * 4096 + b * 256];
    if (k > 0) {
        for (int bin = 255; bin >= 0; --bin) {
            unsigned c = h[bin];
            if (k <= c) { prefix |= ((unsigned)bin) << shift; break; }
            k -= c;
        }
        wsu[OFF_KKC + b] = k;
        wsu[OFF_PREFIX + b] = prefix;
    }
    if (pass == 3) wsf[OFF_THR + b] = funmap(prefix);
}

// ---------------- K3: fused aggregation + OHEM text-dice + final (last block) ---
__global__ __launch_bounds__(NTHR, 4) void k_pix(const float* __restrict__ preds,
                      const int* __restrict__ text,
                      const int* __restrict__ mask,
                      unsigned* __restrict__ wsu,
                      float* __restrict__ out) {
    float* wsf = (float*)wsu;
    const int b = blockIdx.y;
    const int tid = threadIdx.x;
    const int lane = tid & 63;
    __shared__ float stbl[45];
    __shared__ float sred[4];
    __shared__ float sthr;
    __shared__ unsigned sfb;
    __shared__ unsigned s_last;
    __shared__ float sfin[64];
    __shared__ float lt[NB], lk[NB], la[NB], ld[NB];
    if (tid < 45) stbl[tid] = wsf[OFF_TBL + b * 45 + tid];
    if (tid < 4) sred[tid] = 0.f;
    if (tid == 0) { sthr = wsf[OFF_THR + b]; sfb = wsu[OFF_FB + b]; }
    __syncthreads();
    const float thr = sthr;
    const bool fb = sfb != 0u;
    float r_at = 0.f, r_bt = 0.f, r_ct = 0.f, r_ag = 0.f;
    const int* tb = text + b * HW;
    const int* mb = mask + b * HW;
    const float* p0 = preds + (size_t)(b * 6) * HW;
    const float* e0 = preds + (size_t)(b * 6 + 2) * HW;
    const float* e1 = e0 + HW;
    const float* e2 = e0 + 2 * HW;
    const float* e3 = e0 + 3 * HW;

#define BASE_(ci_) (blockIdx.x * (NTHR * 16) + ((ci_) >> 1) * (NTHR * 4) + ((ci_) & 1) * 2 + tid * 4)
#define PLOADC(P, ci_) do {                                                  \
        const int base_ = BASE_(ci_);                                        \
        P##t = *(const int2*)(tb + base_);                                   \
        P##m = *(const int2*)(mb + base_);                                   \
        P##s = *(const float2*)(p0 + base_);                                 \
        P##a = *(const float2*)(e0 + base_);                                 \
        P##b = *(const float2*)(e1 + base_);                                 \
        P##c = *(const float2*)(e2 + base_);                                 \
        P##d = *(const float2*)(e3 + base_);                                 \
    } while (0)

#define PPIX(T, M, S, A, B, C, D) do {                                       \
        bool pos_ = (T) > 0;                                                 \
        bool samp_ = fb ? ((M) > 0) : ((((S) >= thr) || pos_) && ((M) > 0)); \
        float sg_ = 1.f / (1.f + expf(-(S)));                                \
        float smf_ = samp_ ? 1.f : 0.f;                                      \
        float it_ = pos_ ? 1.f : 0.f;                                        \
        r_at += smf_ * sg_ * it_;                                            \
        r_bt += smf_ * sg_ * sg_;                                            \
        r_ct += smf_ * it_;                                                  \
        int t5_ = min((T), 8) * 5;                                           \
        float d0_ = (A) - stbl[t5_ + 0];                                     \
        float d1_ = (B) - stbl[t5_ + 1];                                     \
        float d2_ = (C) - stbl[t5_ + 2];                                     \
        float d3_ = (D) - stbl[t5_ + 3];                                     \
        float w_ = stbl[t5_ + 4];                                            \
        float sq_ = d0_ * d0_ + d1_ * d1_ + d2_ * d2_ + d3_ * d3_;           \
        float dist_ = sqrtf(sq_ + 1e-12f) - 0.5f;                            \
        float hp_ = fmaxf(dist_, 0.f);                                       \
        r_ag += w_ * log1pf(hp_ * hp_);                                      \
    } while (0)

#define PPROC(P) do {                                                        \
        PPIX(P##t.x, P##m.x, P##s.x, P##a.x, P##b.x, P##c.x, P##d.x);        \
        PPIX(P##t.y, P##m.y, P##s.y, P##a.y, P##b.y, P##c.y, P##d.y);        \
    } while (0)

    int2 At, Am;  float2 As, Aa, Ab, Ac, Ad;
    int2 Bt, Bm;  float2 Bs, Ba, Bb, Bc, Bd;

    PLOADC(A, 0);
#pragma unroll 1
    for (int cc = 0; cc < CH2 / 2; ++cc) {
        PLOADC(B, cc * 2 + 1);
        PPROC(A);
        if (cc + 1 < CH2 / 2) PLOADC(A, cc * 2 + 2);
        PPROC(B);
    }
#undef PPROC
#undef PPIX
#undef PLOADC
#undef BASE_

    {
        float v = wred(r_at); if (lane == 0) atomicAdd(&sred[0], v);
        v = wred(r_bt); if (lane == 0) atomicAdd(&sred[1], v);
        v = wred(r_ct); if (lane == 0) atomicAdd(&sred[2], v);
        v = wred(r_ag); if (lane == 0) atomicAdd(&sred[3], v);
    }
    __syncthreads();
    if (tid < 4) {
        const int rep = blockIdx.x & (PREP - 1);
        atomicAdd(&wsf[OFF_PACC + (rep * NB + b) * 4 + tid], sred[tid]);
    }
    // ---- last-block-done: fold the final assembly in (saves a launch) ----
    __threadfence();
    if (tid == 0) {
        unsigned t = atomicAdd(&wsu[OFF_TICK], 1u);
        s_last = (t == (unsigned)(GXS * NB - 1)) ? 1u : 0u;
    }
    __syncthreads();
    if (!s_last) return;
    if (tid < 64) {
        const int bb = tid >> 2, v = tid & 3;
        float s = 0.f;
#pragma unroll
        for (int r = 0; r < PREP; r++)
            s += atomicAdd(&wsf[OFF_PACC + (r * NB + bb) * 4 + v], 0.f);  // coherent read
        sfin[tid] = s;
    }
    __syncthreads();
    if (tid < NB) {
        const float S = 1e-3f;
        float at = sfin[tid * 4 + 0], bt = sfin[tid * 4 + 1];
        float ct = sfin[tid * 4 + 2], ag = sfin[tid * 4 + 3];
        float ak = wsf[OFF_KDICE + tid * 3 + 0];
        float bk = wsf[OFF_KDICE + tid * 3 + 1];
        float ck = wsf[OFF_KDICE + tid * 3 + 2];
        lt[tid] = 1.f - 2.f * (at + S) / ((bt + S) + (ct + S));
        lk[tid] = 1.f - 2.f * (ak + S) / ((bk + S) + (ck + S));
        int nval = (int)wsu[OFF_NVAL + tid];
        la[tid] = (nval > 0) ? ag / fmaxf((float)nval, 1.f) : 0.f;
        ld[tid] = wsf[OFF_DISCR + tid];
    }
    __syncthreads();
    if (tid == 0) {
        float st = 0, sk = 0, sa = 0, sd = 0;
        for (int i = 0; i < NB; i++) { st += lt[i]; sk += lk[i]; sa += la[i]; sd += ld[i]; }
        out[0] = st / NB;
        out[1] = 0.5f * sk / NB;
        out[2] = 0.25f * sa / NB;
        out[3] = 0.25f * sd / NB;
    }
}

extern "C" void kernel_launch(void* const* d_in, const int* in_sizes, int n_in,
                              void* d_out, int out_size, void* d_ws, size_t ws_size,
                              hipStream_t stream) {
    const float* preds = (const float*)d_in[0];
    const int* text = (const int*)d_in[1];
    const int* kern = (const int*)d_in[2];
    const int* mask = (const int*)d_in[3];
    unsigned* wsu = (unsigned*)d_ws;
    float* out = (float*)d_out;

    const int do_compact = (ws_size >= WS_FULL_BYTES) ? 1 : 0;

    dim3 grid(GXS, NB);
    k_stats<<<grid, NTHR, 0, stream>>>(preds, text, kern, mask, wsu, do_compact);
    k_sel<<<NB, NTHR, 0, stream>>>(wsu, do_compact);
    if (!do_compact) {
        (void)hipMemsetAsync((char*)d_ws + (size_t)OFF_HISTFB * 4, 0,
                             (size_t)4 * 16 * 256 * 4, stream);
        dim3 hgrid(128, NB);
        for (int pass = 0; pass < 4; pass++) {
            k_hist<<<hgrid, NTHR, 0, stream>>>(preds, text, wsu, pass);
            k_select<<<1, 64, 0, stream>>>(wsu, pass);
        }
    }
    k_pix<<<grid, NTHR, 0, stream>>>(preds, text, mask, wsu, out);
}

// Round 3
// 254.185 us; speedup vs baseline: 1.3652x; 1.3652x over previous
//
#include <hip/hip_runtime.h>
#include <math.h>

#define HW (512 * 512)
#define NB 16
#define NTHR 256
#define GXS 64          // blocks per batch: 64 blocks * 256 thr * 16 px = HW
#define NSEG 256        // waves per batch = segments
#define SEGSZ 1024      // max keys per segment (16 px * 64 lanes)
#define PREP 4          // replicas for k_pix accumulator atomics

// ---- workspace layout (4-byte words). NOTHING needs pre-zeroing in the
// compaction path: k_stats writes per-block partial slots (plain stores),
// k_sel zeroes PACC for k_pix/k_final. ----
#define OFF_ACC    0                           // f [NB][GXS][52] per-block partials
#define OFF_NEGMX  (OFF_ACC + NB * GXS * 52)   // u [NB][GXS] per-block max(~negkey)
#define OFF_PACC   (OFF_NEGMX + NB * GXS)      // f [PREP][NB][4] (zeroed by k_sel)
#define OFF_KDICE  (OFF_PACC + PREP * NB * 4)  // f [NB][3] ak,bk,ck
#define OFF_TBL    (OFF_KDICE + NB * 3)        // f [NB][9][5] rows0..8={a0..a3,w}
#define OFF_THR    (OFF_TBL + NB * 45)         // f [NB]
#define OFF_FB     (OFF_THR + NB)              // u [NB]
#define OFF_NVAL   (OFF_FB + NB)               // u [NB]
#define OFF_DISCR  (OFF_NVAL + NB)             // f [NB]
#define OFF_PREFIX (OFF_DISCR + NB)            // u [NB] fallback select state
#define OFF_KKC    (OFF_PREFIX + NB)           // u [NB]
#define OFF_NEGC   (OFF_KKC + NB)              // u [NB]
#define OFF_HISTFB (OFF_NEGC + NB)             // u [4][16][256] fallback hists
#define OFF_CNTS   (OFF_HISTFB + 4 * 16 * 256) // u [NB][NSEG] per-wave seg counts
#define OFF_KEYS   (OFF_CNTS + NB * NSEG)      // u [NB][NSEG][SEGSZ] compacted keys
#define WS_FULL_BYTES ((size_t)(OFF_KEYS + NB * HW) * 4)

// acc value indices: 0-7 kcnt, 8-15 tcnt, 16-47 ksum, 48 pos, 49 ak, 50 bk, 51 ck

__device__ __forceinline__ unsigned fmap(float f) {
    unsigned u = __float_as_uint(f);
    return (u & 0x80000000u) ? ~u : (u | 0x80000000u);
}
__device__ __forceinline__ float funmap(unsigned u) {
    return (u & 0x80000000u) ? __uint_as_float(u & 0x7FFFFFFFu)
                             : __uint_as_float(~u);
}
__device__ __forceinline__ float wred(float x) {
#pragma unroll
    for (int o = 32; o; o >>= 1) x += __shfl_xor(x, o);
    return x;
}
__device__ __forceinline__ unsigned wredu(unsigned x) {
#pragma unroll
    for (int o = 32; o; o >>= 1) x += __shfl_xor(x, o);
    return x;
}
__device__ __forceinline__ unsigned wredumax(unsigned x) {
#pragma unroll
    for (int o = 32; o; o >>= 1) x = max(x, (unsigned)__shfl_xor((int)x, o));
    return x;
}
__device__ __forceinline__ unsigned long long wredull(unsigned long long x) {
#pragma unroll
    for (int o = 32; o; o >>= 1)
        x += (unsigned long long)__shfl_xor((unsigned long long)x, o);
    return x;
}

// ---------------- K1: stats + kernel-dice + segment compaction ----------------
// Round-2 lesson: the compiler SINKS source-level prefetch (VGPR fell to 36) and
// float2 loads doubled VMEM count -> regression. This version keeps the proven
// 4-px int4/float4 chunks and pins the A/B prefetch with sched_barrier(0):
// loads for chunk n+1 are fenced above the compute of chunk n, so both register
// buffers stay live (~120 VGPR expected; still 4 waves/SIMD at 512-reg pool).
__global__ __launch_bounds__(NTHR, 2) void k_stats(const float* __restrict__ preds,
                        const int* __restrict__ text,
                        const int* __restrict__ kern,
                        const int* __restrict__ mask,
                        unsigned* __restrict__ wsu, int do_compact) {
    float* wsf = (float*)wsu;
    const int b = blockIdx.y;
    const int tid = threadIdx.x;
    const int lane = tid & 63;
    const unsigned long long lmask = (1ull << lane) - 1ull;
    __shared__ float sacc[52];
    __shared__ unsigned smx;
    if (tid < 52) sacc[tid] = 0.f;
    if (tid == 0) smx = 0u;
    __syncthreads();

    const int* tb = text + b * HW;
    const int* kb = kern + b * HW;
    const int* mb = mask + b * HW;
    const float* p0 = preds + (size_t)(b * 6 + 0) * HW;
    const float* p1 = preds + (size_t)(b * 6 + 1) * HW;
    const float* e0 = preds + (size_t)(b * 6 + 2) * HW;
    const float* e1 = e0 + HW;
    const float* e2 = e0 + 2 * HW;
    const float* e3 = e0 + 3 * HW;

    const int seg = blockIdx.x * 4 + (tid >> 6);
    unsigned* keys = wsu + OFF_KEYS + (size_t)b * HW + (size_t)seg * SEGSZ;
    unsigned segoff = 0;
    unsigned mkAll = 0u;

    float ks[32];
#pragma unroll
    for (int i = 0; i < 32; i++) ks[i] = 0.f;
    float r_ak = 0.f, r_bk = 0.f, r_ck = 0.f, r_pos = 0.f;
    unsigned kcW[8] = {0, 0, 0, 0, 0, 0, 0, 0};
    unsigned long long tpack = 0ull;  // 8x8-bit per-thread text-counts (<=16/field)

#define BASE4_(ci_) (blockIdx.x * (NTHR * 16) + (ci_) * (NTHR * 4) + tid * 4)

#define LOADC(P, ci_) do {                                                   \
        const int base_ = BASE4_(ci_);                                      \
        P##t = *(const int4*)(tb + base_);                                  \
        P##k = *(const int4*)(kb + base_);                                  \
        P##m = *(const int4*)(mb + base_);                                  \
        P##s = *(const float4*)(p0 + base_);                                \
        P##q = *(const float4*)(p1 + base_);                                \
        P##a = *(const float4*)(e0 + base_);                                \
        P##b = *(const float4*)(e1 + base_);                                \
        P##c = *(const float4*)(e2 + base_);                                \
        P##d = *(const float4*)(e3 + base_);                                \
    } while (0)

#define PIX(T, K, M, Q, A, B, C, D) do {                                     \
        bool pos_ = (T) > 0, mp_ = (M) > 0;                                  \
        float sm_ = (pos_ && mp_) ? 1.f : 0.f;                               \
        float sg_ = 1.f / (1.f + expf(-(Q)));                                \
        float ik_ = ((K) > 0) ? 1.f : 0.f;                                   \
        r_ak += sm_ * sg_ * ik_;                                             \
        r_bk += sm_ * sg_ * sg_;                                             \
        r_ck += sm_ * ik_;                                                   \
        r_pos += sm_;                                                        \
        tpack += pos_ ? (1ull << ((((unsigned)(T) - 1u) & 7u) * 8u)) : 0ull; \
        _Pragma("unroll")                                                    \
        for (int i_ = 0; i_ < 8; i_++) {                                     \
            bool hit_ = ((K) == i_ + 1);                                     \
            kcW[i_] += (unsigned)__popcll(__ballot(hit_));                   \
            float h_ = hit_ ? 1.f : 0.f;                                     \
            ks[i_ * 4 + 0] += h_ * (A);                                      \
            ks[i_ * 4 + 1] += h_ * (B);                                      \
            ks[i_ * 4 + 2] += h_ * (C);                                      \
            ks[i_ * 4 + 3] += h_ * (D);                                      \
        }                                                                    \
    } while (0)

#define PROC4(P) do {                                                           \
        PIX(P##t.x, P##k.x, P##m.x, P##q.x, P##a.x, P##b.x, P##c.x, P##d.x);    \
        PIX(P##t.y, P##k.y, P##m.y, P##q.y, P##a.y, P##b.y, P##c.y, P##d.y);    \
        PIX(P##t.z, P##k.z, P##m.z, P##q.z, P##a.z, P##b.z, P##c.z, P##d.z);    \
        PIX(P##t.w, P##k.w, P##m.w, P##q.w, P##a.w, P##b.w, P##c.w, P##d.w);    \
        const unsigned long long m0_ = __ballot(P##t.x == 0);                   \
        const unsigned long long m1_ = __ballot(P##t.y == 0);                   \
        const unsigned long long m2_ = __ballot(P##t.z == 0);                   \
        const unsigned long long m3_ = __ballot(P##t.w == 0);                   \
        const unsigned c0_ = (unsigned)__popcll(m0_);                           \
        const unsigned c1_ = (unsigned)__popcll(m1_);                           \
        const unsigned c2_ = (unsigned)__popcll(m2_);                           \
        const unsigned c3_ = (unsigned)__popcll(m3_);                           \
        if (do_compact) {                                                       \
            if (P##t.x == 0)                                                    \
                keys[segoff + (unsigned)__popcll(m0_ & lmask)] = fmap(P##s.x);  \
            if (P##t.y == 0)                                                    \
                keys[segoff + c0_ + (unsigned)__popcll(m1_ & lmask)] = fmap(P##s.y); \
            if (P##t.z == 0)                                                    \
                keys[segoff + c0_ + c1_ + (unsigned)__popcll(m2_ & lmask)] = fmap(P##s.z); \
            if (P##t.w == 0)                                                    \
                keys[segoff + c0_ + c1_ + c2_ + (unsigned)__popcll(m3_ & lmask)] = fmap(P##s.w); \
        }                                                                       \
        segoff += c0_ + c1_ + c2_ + c3_;                                        \
        unsigned mk_ = 0u;                                                      \
        if (P##t.x == 0) mk_ = max(mk_, ~fmap(P##s.x));                         \
        if (P##t.y == 0) mk_ = max(mk_, ~fmap(P##s.y));                         \
        if (P##t.z == 0) mk_ = max(mk_, ~fmap(P##s.z));                         \
        if (P##t.w == 0) mk_ = max(mk_, ~fmap(P##s.w));                         \
        mkAll = max(mkAll, mk_);                                                \
    } while (0)

    int4 At, Ak, Am;  float4 As, Aq, Aa, Ab, Ac, Ad;
    int4 Bt, Bk, Bm;  float4 Bs, Bq, Ba, Bb, Bc, Bd;

    // manual A/B pipeline over the 4 chunks; sched_barrier(0) pins each
    // prefetch-issue above the previous chunk's compute.
    LOADC(A, 0);
    LOADC(B, 1);
    __builtin_amdgcn_sched_barrier(0);
    PROC4(A);                 // chunk 0 (B's loads in flight)
    LOADC(A, 2);
    __builtin_amdgcn_sched_barrier(0);
    PROC4(B);                 // chunk 1 (A's loads in flight)
    LOADC(B, 3);
    __builtin_amdgcn_sched_barrier(0);
    PROC4(A);                 // chunk 2 (B's loads in flight)
    PROC4(B);                 // chunk 3
#undef PROC4
#undef PIX
#undef LOADC
#undef BASE4_

    if (lane == 0) wsu[OFF_CNTS + b * NSEG + seg] = segoff;
    mkAll = wredumax(mkAll);
    if (lane == 0) atomicMax(&smx, mkAll);

    // ---- epilogue: wave butterfly -> LDS -> one plain per-block store ----
#pragma unroll
    for (int i = 0; i < 32; i++) {
        float v = wred(ks[i]);
        if (lane == 0) atomicAdd(&sacc[16 + i], v);
    }
    {
        float v = wred(r_ak); if (lane == 0) atomicAdd(&sacc[49], v);
        v = wred(r_bk); if (lane == 0) atomicAdd(&sacc[50], v);
        v = wred(r_ck); if (lane == 0) atomicAdd(&sacc[51], v);
        v = wred(r_pos); if (lane == 0) atomicAdd(&sacc[48], v);
    }
    {
        // unpack 8x8-bit -> 2x(4x16-bit) so the 64-lane sum can't overflow
        unsigned long long lo = tpack & 0x00FF00FF00FF00FFull;          // inst 1,3,5,7
        unsigned long long hi = (tpack >> 8) & 0x00FF00FF00FF00FFull;   // inst 2,4,6,8
        lo = wredull(lo);
        hi = wredull(hi);
        if (lane == 0) {
            atomicAdd(&sacc[8 + 0], (float)(unsigned)( lo        & 0xFFFFull));
            atomicAdd(&sacc[8 + 2], (float)(unsigned)((lo >> 16) & 0xFFFFull));
            atomicAdd(&sacc[8 + 4], (float)(unsigned)((lo >> 32) & 0xFFFFull));
            atomicAdd(&sacc[8 + 6], (float)(unsigned)((lo >> 48) & 0xFFFFull));
            atomicAdd(&sacc[8 + 1], (float)(unsigned)( hi        & 0xFFFFull));
            atomicAdd(&sacc[8 + 3], (float)(unsigned)((hi >> 16) & 0xFFFFull));
            atomicAdd(&sacc[8 + 5], (float)(unsigned)((hi >> 32) & 0xFFFFull));
            atomicAdd(&sacc[8 + 7], (float)(unsigned)((hi >> 48) & 0xFFFFull));
        }
    }
    if (lane == 0) {
#pragma unroll
        for (int i = 0; i < 8; i++) atomicAdd(&sacc[i], (float)kcW[i]);
    }
    __syncthreads();
    if (tid < 52)
        wsf[OFF_ACC + (b * GXS + blockIdx.x) * 52 + tid] = sacc[tid];
    if (tid == 0)
        wsu[OFF_NEGMX + b * GXS + blockIdx.x] = smx;
}

// ---------------- K2: partial-sum + setup + OHEM threshold ----------------
__global__ void k_sel(unsigned* __restrict__ wsu, int do_select) {
    float* wsf = (float*)wsu;
    const int b = blockIdx.x;
    const int tid = threadIdx.x;   // 256 threads; tid == segment id
    const int lane = tid & 63;
    __shared__ float s_acc[52];
    __shared__ float s_avg[8][4];
    __shared__ int s_valid[8];
    __shared__ unsigned s_hist[256];
    __shared__ unsigned s_negtot;
    __shared__ unsigned s_negmax;
    __shared__ unsigned s_kk, s_prefix;

    if (tid < 52) {
        float v = 0.f;
        const float* p = wsf + OFF_ACC + b * GXS * 52 + tid;
#pragma unroll 8
        for (int r = 0; r < GXS; r++) v += p[r * 52];
        s_acc[tid] = v;
    }
    if (tid == 0) s_negtot = 0u;
    // zero the k_pix accumulators (block 0 only)
    if (b == 0 && tid < PREP * NB * 4) wsf[OFF_PACC + tid] = 0.f;
    __syncthreads();

    const unsigned myc = wsu[OFF_CNTS + b * NSEG + tid];
    {
        unsigned cw = wredu(myc);
        if (lane == 0) atomicAdd(&s_negtot, cw);
    }
    if (tid < 64) {
        unsigned m = wsu[OFF_NEGMX + b * GXS + tid];
        m = wredumax(m);
        if (tid == 0) s_negmax = m;
    }
    if (tid < 8) {
        float kcf = s_acc[tid];
        float tcf = s_acc[8 + tid];
        int valid = (kcf > 0.f && tcf > 0.f) ? 1 : 0;
        float inv = 1.f / fmaxf(kcf, 1.f);
        float w = valid ? 1.f / fmaxf(tcf, 1.f) : 0.f;
#pragma unroll
        for (int c = 0; c < 4; c++) {
            float a = s_acc[16 + tid * 4 + c] * inv;
            s_avg[tid][c] = a;
            wsf[OFF_TBL + b * 45 + (tid + 1) * 5 + c] = a;
        }
        s_valid[tid] = valid;
        wsf[OFF_TBL + b * 45 + (tid + 1) * 5 + 4] = w;
    }
    if (tid >= 8 && tid < 13) wsf[OFF_TBL + b * 45 + (tid - 8)] = 0.f;  // bg row
    if (tid >= 16 && tid < 19) wsf[OFF_KDICE + b * 3 + (tid - 16)] = s_acc[49 + (tid - 16)];
    __syncthreads();
    if (tid == 0) {
        int nval = 0;
        for (int i = 0; i < 8; i++) nval += s_valid[i];
        float L = 0.f;
        for (int i = 0; i < 8; i++)
            for (int j = i + 1; j < 8; j++)
                if (s_valid[i] && s_valid[j]) {
                    float sq = 0.f;
                    for (int c = 0; c < 4; c++) {
                        float d = s_avg[i][c] - s_avg[j][c];
                        sq += d * d;
                    }
                    float h = fmaxf(3.0f - sqrtf(sq), 0.f);
                    L += log1pf(h * h);
                }
        wsf[OFF_DISCR + b] = (nval > 1) ? L / fmaxf((float)(nval * (nval - 1)), 1.f) : 0.f;
        wsu[OFF_NVAL + b] = (unsigned)nval;
        unsigned pos = (unsigned)s_acc[48];
        unsigned neg = s_negtot;
        wsu[OFF_NEGC + b] = neg;
        unsigned nn = min(pos * 3u, neg);
        int fb = (pos == 0u || nn == 0u) ? 1 : 0;
        wsu[OFF_FB + b] = (unsigned)fb;
        wsu[OFF_KKC + b] = fb ? 0u : nn;   // fallback path state
        wsu[OFF_PREFIX + b] = 0u;
        wsf[OFF_THR + b] = 0.f;
        unsigned kk = fb ? 0u : nn;
        if (!fb && nn == neg) {
            // fast path: threshold = min negative score
            wsf[OFF_THR + b] = funmap(~s_negmax);
            kk = 0u;                        // skip radix
        }
        s_kk = kk;
        s_prefix = 0u;
    }
    __syncthreads();
    if (!do_select) return;
    if (s_kk == 0u) return;                 // uniform: fb or fast path
    const unsigned* keys = wsu + OFF_KEYS + (size_t)b * HW + (size_t)tid * SEGSZ;
    unsigned prefix = 0u;
    for (int pass = 0; pass < 4; pass++) {
        const int shift = 24 - 8 * pass;
        const unsigned fmask = (pass == 0) ? 0u : (0xFFFFFFFFu << (shift + 8));
        s_hist[tid] = 0u;
        __syncthreads();
        for (unsigned i = 0; i < myc; i++) {
            unsigned key = keys[i];
            if ((key & fmask) == prefix) atomicAdd(&s_hist[(key >> shift) & 255u], 1u);
        }
        __syncthreads();
        if (tid == 0) {
            unsigned k2 = s_kk;
            for (int bin = 255; bin >= 0; --bin) {
                unsigned c = s_hist[bin];
                if (k2 <= c) { s_prefix = prefix | (((unsigned)bin) << shift); s_kk = k2; break; }
                k2 -= c;
            }
        }
        __syncthreads();
        prefix = s_prefix;
    }
    if (tid == 0) wsf[OFF_THR + b] = funmap(prefix);
}

// ---------------- fallback radix select over raw data (only if ws too small) ----------------
__global__ void k_hist(const float* __restrict__ preds, const int* __restrict__ text,
                       unsigned* __restrict__ wsu, int pass) {
    const int b = blockIdx.y;
    const int tid = threadIdx.x;
    __shared__ unsigned h[256];
    h[tid] = 0u;
    __syncthreads();
    const unsigned prefix = wsu[OFF_PREFIX + b];
    const int shift = 24 - 8 * pass;
    const unsigned fmask = (pass == 0) ? 0u : (0xFFFFFFFFu << (shift + 8));
    const int* tb = text + b * HW;
    const float* pt = preds + (size_t)(b * 6) * HW;
    for (int p = blockIdx.x * NTHR + tid; p < HW; p += gridDim.x * NTHR) {
        if (tb[p] == 0) {
            unsigned key = fmap(pt[p]);
            if ((key & fmask) == prefix) atomicAdd(&h[(key >> shift) & 255u], 1u);
        }
    }
    __syncthreads();
    if (h[tid]) atomicAdd(&wsu[OFF_HISTFB + pass * 4096 + b * 256 + tid], h[tid]);
}
__global__ void k_select(unsigned* __restrict__ wsu, int pass) {
    int b = threadIdx.x;
    if (b >= NB) return;
    float* wsf = (float*)wsu;
    unsigned k = wsu[OFF_KKC + b];
    unsigned prefix = wsu[OFF_PREFIX + b];
    const int shift = 24 - 8 * pass;
    const unsigned* h = &wsu[OFF_HISTFB + pass * 4096 + b * 256];
    if (k > 0) {
        for (int bin = 255; bin >= 0; --bin) {
            unsigned c = h[bin];
            if (k <= c) { prefix |= ((unsigned)bin) << shift; break; }
            k -= c;
        }
        wsu[OFF_KKC + b] = k;
        wsu[OFF_PREFIX + b] = prefix;
    }
    if (pass == 3) wsf[OFF_THR + b] = funmap(prefix);
}

// ---------------- K3: fused aggregation + OHEM text-dice ----------------
__global__ __launch_bounds__(NTHR, 2) void k_pix(const float* __restrict__ preds,
                      const int* __restrict__ text,
                      const int* __restrict__ mask,
                      unsigned* __restrict__ wsu) {
    float* wsf = (float*)wsu;
    const int b = blockIdx.y;
    const int tid = threadIdx.x;
    const int lane = tid & 63;
    __shared__ float stbl[45];
    __shared__ float sred[4];
    __shared__ float sthr;
    __shared__ unsigned sfb;
    if (tid < 45) stbl[tid] = wsf[OFF_TBL + b * 45 + tid];
    if (tid < 4) sred[tid] = 0.f;
    if (tid == 0) { sthr = wsf[OFF_THR + b]; sfb = wsu[OFF_FB + b]; }
    __syncthreads();
    const float thr = sthr;
    const bool fb = sfb != 0u;
    float r_at = 0.f, r_bt = 0.f, r_ct = 0.f, r_ag = 0.f;
    const int* tb = text + b * HW;
    const int* mb = mask + b * HW;
    const float* p0 = preds + (size_t)(b * 6) * HW;
    const float* e0 = preds + (size_t)(b * 6 + 2) * HW;
    const float* e1 = e0 + HW;
    const float* e2 = e0 + 2 * HW;
    const float* e3 = e0 + 3 * HW;

#define BASE4_(ci_) (blockIdx.x * (NTHR * 16) + (ci_) * (NTHR * 4) + tid * 4)
#define PLOADC(P, ci_) do {                                                  \
        const int base_ = BASE4_(ci_);                                      \
        P##t = *(const int4*)(tb + base_);                                  \
        P##m = *(const int4*)(mb + base_);                                  \
        P##s = *(const float4*)(p0 + base_);                                \
        P##a = *(const float4*)(e0 + base_);                                \
        P##b = *(const float4*)(e1 + base_);                                \
        P##c = *(const float4*)(e2 + base_);                                \
        P##d = *(const float4*)(e3 + base_);                                \
    } while (0)

#define PPIX(T, M, S, A, B, C, D) do {                                       \
        bool pos_ = (T) > 0;                                                 \
        bool samp_ = fb ? ((M) > 0) : ((((S) >= thr) || pos_) && ((M) > 0)); \
        float sg_ = 1.f / (1.f + expf(-(S)));                                \
        float smf_ = samp_ ? 1.f : 0.f;                                      \
        float it_ = pos_ ? 1.f : 0.f;                                        \
        r_at += smf_ * sg_ * it_;                                            \
        r_bt += smf_ * sg_ * sg_;                                            \
        r_ct += smf_ * it_;                                                  \
        int t5_ = min((T), 8) * 5;                                           \
        float d0_ = (A) - stbl[t5_ + 0];                                     \
        float d1_ = (B) - stbl[t5_ + 1];                                     \
        float d2_ = (C) - stbl[t5_ + 2];                                     \
        float d3_ = (D) - stbl[t5_ + 3];                                     \
        float w_ = stbl[t5_ + 4];                                            \
        float sq_ = d0_ * d0_ + d1_ * d1_ + d2_ * d2_ + d3_ * d3_;           \
        float dist_ = sqrtf(sq_ + 1e-12f) - 0.5f;                            \
        float hp_ = fmaxf(dist_, 0.f);                                       \
        r_ag += w_ * log1pf(hp_ * hp_);                                      \
    } while (0)

#define PPROC4(P) do {                                                       \
        PPIX(P##t.x, P##m.x, P##s.x, P##a.x, P##b.x, P##c.x, P##d.x);        \
        PPIX(P##t.y, P##m.y, P##s.y, P##a.y, P##b.y, P##c.y, P##d.y);        \
        PPIX(P##t.z, P##m.z, P##s.z, P##a.z, P##b.z, P##c.z, P##d.z);        \
        PPIX(P##t.w, P##m.w, P##s.w, P##a.w, P##b.w, P##c.w, P##d.w);        \
    } while (0)

    int4 At, Am;  float4 As, Aa, Ab, Ac, Ad;
    int4 Bt, Bm;  float4 Bs, Ba, Bb, Bc, Bd;

    PLOADC(A, 0);
    PLOADC(B, 1);
    __builtin_amdgcn_sched_barrier(0);
    PPROC4(A);
    PLOADC(A, 2);
    __builtin_amdgcn_sched_barrier(0);
    PPROC4(B);
    PLOADC(B, 3);
    __builtin_amdgcn_sched_barrier(0);
    PPROC4(A);
    PPROC4(B);
#undef PPROC4
#undef PPIX
#undef PLOADC
#undef BASE4_

    {
        float v = wred(r_at); if (lane == 0) atomicAdd(&sred[0], v);
        v = wred(r_bt); if (lane == 0) atomicAdd(&sred[1], v);
        v = wred(r_ct); if (lane == 0) atomicAdd(&sred[2], v);
        v = wred(r_ag); if (lane == 0) atomicAdd(&sred[3], v);
    }
    __syncthreads();
    if (tid < 4) {
        const int rep = blockIdx.x & (PREP - 1);
        atomicAdd(&wsf[OFF_PACC + (rep * NB + b) * 4 + tid], sred[tid]);
    }
}

// ---------------- K4: final assembly ----------------
__global__ void k_final(unsigned* __restrict__ wsu, float* __restrict__ out) {
    float* wsf = (float*)wsu;
    __shared__ float lt[NB], lk[NB], la[NB], ld[NB];
    int b = threadIdx.x;
    if (b < NB) {
        const float S = 1e-3f;
        float at = 0.f, bt = 0.f, ct = 0.f, ag = 0.f;
#pragma unroll
        for (int r = 0; r < PREP; r++) {
            at += wsf[OFF_PACC + (r * NB + b) * 4 + 0];
            bt += wsf[OFF_PACC + (r * NB + b) * 4 + 1];
            ct += wsf[OFF_PACC + (r * NB + b) * 4 + 2];
            ag += wsf[OFF_PACC + (r * NB + b) * 4 + 3];
        }
        float ak = wsf[OFF_KDICE + b * 3 + 0];
        float bk = wsf[OFF_KDICE + b * 3 + 1];
        float ck = wsf[OFF_KDICE + b * 3 + 2];
        lt[b] = 1.f - 2.f * (at + S) / ((bt + S) + (ct + S));
        lk[b] = 1.f - 2.f * (ak + S) / ((bk + S) + (ck + S));
        int nval = (int)wsu[OFF_NVAL + b];
        la[b] = (nval > 0) ? ag / fmaxf((float)nval, 1.f) : 0.f;
        ld[b] = wsf[OFF_DISCR + b];
    }
    __syncthreads();
    if (b == 0) {
        float st = 0, sk = 0, sa = 0, sd = 0;
        for (int i = 0; i < NB; i++) { st += lt[i]; sk += lk[i]; sa += la[i]; sd += ld[i]; }
        out[0] = st / NB;
        out[1] = 0.5f * sk / NB;
        out[2] = 0.25f * sa / NB;
        out[3] = 0.25f * sd / NB;
    }
}

extern "C" void kernel_launch(void* const* d_in, const int* in_sizes, int n_in,
                              void* d_out, int out_size, void* d_ws, size_t ws_size,
                              hipStream_t stream) {
    const float* preds = (const float*)d_in[0];
    const int* text = (const int*)d_in[1];
    const int* kern = (const int*)d_in[2];
    const int* mask = (const int*)d_in[3];
    unsigned* wsu = (unsigned*)d_ws;
    float* out = (float*)d_out;

    const int do_compact = (ws_size >= WS_FULL_BYTES) ? 1 : 0;

    dim3 grid(GXS, NB);
    k_stats<<<grid, NTHR, 0, stream>>>(preds, text, kern, mask, wsu, do_compact);
    k_sel<<<NB, NTHR, 0, stream>>>(wsu, do_compact);
    if (!do_compact) {
        (void)hipMemsetAsync((char*)d_ws + (size_t)OFF_HISTFB * 4, 0,
                             (size_t)4 * 16 * 256 * 4, stream);
        dim3 hgrid(128, NB);
        for (int pass = 0; pass < 4; pass++) {
            k_hist<<<hgrid, NTHR, 0, stream>>>(preds, text, wsu, pass);
            k_select<<<1, 64, 0, stream>>>(wsu, pass);
        }
    }
    k_pix<<<grid, NTHR, 0, stream>>>(preds, text, mask, wsu);
    k_final<<<1, 64, 0, stream>>>(wsu, out);
}